// Round 15
// baseline (256.417 us; speedup 1.0000x reference)
//
#include <hip/hip_runtime.h>
#include <math.h>

#define D_MODEL 1024
#define T_SEQ   1024
#define BATCH   4
#define NHEAD   16
#define HDIM    64

// keep counts: trunc(linspace(0.35,0.15,16)*64), min 1
__constant__ int KEEPC[16] = {22,21,20,19,18,18,17,16,15,14,13,13,12,11,10,9};

typedef short bh8  __attribute__((ext_vector_type(8)));
typedef float f32x4 __attribute__((ext_vector_type(4)));
typedef int   i32x4 __attribute__((ext_vector_type(4)));

__device__ __forceinline__ unsigned short f2bf(float f) {
    unsigned int u = __float_as_uint(f);
    return (unsigned short)((u + 0x7FFFu + ((u >> 16) & 1u)) >> 16);
}
__device__ __forceinline__ float bf2f(unsigned short h) {
    return __uint_as_float(((unsigned int)h) << 16);
}

// ---------------------------------------------------------------------------
// cast_prep:
//  kw -> (hi,lo) bf16; vw, ow -> bf16;
//  x  -> (a) base-256 digit planes FRAGMENT-MAJOR for gemm_q (verified r11);
//        (b) bf16 hi/lo planes xh/xl ROW-MAJOR for gemm_kv (verified r12);
//  qw -> sign int8 fragment-major.
// ---------------------------------------------------------------------------
__global__ void cast_prep(const float* __restrict__ kw,
                          unsigned short* __restrict__ kwh,
                          unsigned short* __restrict__ kwl,
                          const float* __restrict__ vw,
                          unsigned short* __restrict__ vwb,
                          const float* __restrict__ ow,
                          unsigned short* __restrict__ owb,
                          const float* __restrict__ x,
                          signed char* __restrict__ dig,
                          unsigned short* __restrict__ xh,
                          unsigned short* __restrict__ xl,
                          const float* __restrict__ qw,
                          signed char* __restrict__ sg)
{
    const int NS = (D_MODEL * D_MODEL) / 8;          // 131072
    const int NX = (BATCH * T_SEQ * D_MODEL) / 8;    // 524288
    int i = blockIdx.x * 256 + threadIdx.x;

    if (i < 3 * NS) {
        const float* src; unsigned short* dh; unsigned short* dl = nullptr;
        long off;
        if (i < NS)          { src = kw; dh = kwh; dl = kwl; off = i; }
        else if (i < 2 * NS) { src = vw; dh = vwb; off = i - NS; }
        else                 { src = ow; dh = owb; off = i - 2 * NS; }
        long e = off * 8;
        alignas(16) float fl[8];
        *(float4*)&fl[0] = *(const float4*)(src + e);
        *(float4*)&fl[4] = *(const float4*)(src + e + 4);
        uint4 hp, lp;
        unsigned int* hpw = (unsigned int*)&hp;
        unsigned int* lpw = (unsigned int*)&lp;
        #pragma unroll
        for (int c = 0; c < 4; c++) {
            unsigned short h0 = f2bf(fl[2 * c]), h1 = f2bf(fl[2 * c + 1]);
            hpw[c] = (unsigned int)h0 | ((unsigned int)h1 << 16);
            if (dl) {
                unsigned short l0 = f2bf(fl[2 * c] - bf2f(h0));
                unsigned short l1 = f2bf(fl[2 * c + 1] - bf2f(h1));
                lpw[c] = (unsigned int)l0 | ((unsigned int)l1 << 16);
            }
        }
        *(uint4*)(dh + e) = hp;
        if (dl) *(uint4*)(dl + e) = lp;
    } else if (i < 3 * NS + NX) {
        long e = (long)(i - 3 * NS) * 8;
        alignas(16) float f[8];
        *(float4*)&f[0] = *(const float4*)(x + e);
        *(float4*)&f[4] = *(const float4*)(x + e + 4);
        signed char d[4][8];
        #pragma unroll
        for (int c = 0; c < 8; c++) {
            int n = (int)rintf(f[c] * 8388608.0f);
            int d0 = (signed char)(n & 0xff); n = (n - d0) >> 8;
            int d1 = (signed char)(n & 0xff); n = (n - d1) >> 8;
            int d2 = (signed char)(n & 0xff); n = (n - d2) >> 8;
            d[0][c] = (signed char)d0; d[1][c] = (signed char)d1;
            d[2][c] = (signed char)d2; d[3][c] = (signed char)n;
        }
        // fragment-major: dig[rt][kstep][p][L][16], L = rg*16 + (row&15)
        long row = e >> 10;
        int  kk  = (int)(e & 1023);
        long rt  = row >> 4;
        int  l15r = (int)(row & 15);
        int  kstep = kk >> 6;
        int  rg2 = (kk >> 4) & 3;
        int  L = rg2 * 16 + l15r;
        int  t = kk & 15;                       // 0 or 8
        signed char* dp = dig + (rt << 16) + ((long)kstep << 12)
                              + ((long)L << 4) + t;
        #pragma unroll
        for (int p = 0; p < 4; p++)
            *(uint2*)(dp + (p << 10)) = *(uint2*)&d[p][0];
        // bf16 hi/lo planes (row-major) for gemm_kv
        uint4 hp, lp;
        unsigned int* hpw = (unsigned int*)&hp;
        unsigned int* lpw = (unsigned int*)&lp;
        #pragma unroll
        for (int c = 0; c < 4; c++) {
            unsigned short h0 = f2bf(f[2 * c]), h1 = f2bf(f[2 * c + 1]);
            hpw[c] = (unsigned int)h0 | ((unsigned int)h1 << 16);
            unsigned short l0 = f2bf(f[2 * c] - bf2f(h0));
            unsigned short l1 = f2bf(f[2 * c + 1] - bf2f(h1));
            lpw[c] = (unsigned int)l0 | ((unsigned int)l1 << 16);
        }
        *(uint4*)(xh + e) = hp;
        *(uint4*)(xl + e) = lp;
    } else if (i < 3 * NS + NX + NS) {
        long e = (long)(i - 3 * NS - NX) * 8;
        alignas(16) float f[8];
        *(float4*)&f[0] = *(const float4*)(qw + e);
        *(float4*)&f[4] = *(const float4*)(qw + e + 4);
        signed char s[8];
        #pragma unroll
        for (int c = 0; c < 8; c++)
            s[c] = (signed char)((f[c] > 0.f) - (f[c] < 0.f));
        // fragment-major: sg[ct][kstep][L][16], L = rg*16 + (col&15)
        long col = e >> 10;
        int  kk  = (int)(e & 1023);
        long ct  = col >> 4;
        int  l15c = (int)(col & 15);
        int  kstep = kk >> 6;
        int  rg2 = (kk >> 4) & 3;
        int  L = rg2 * 16 + l15c;
        int  t = kk & 15;
        signed char* sp = sg + (ct << 14) + ((long)kstep << 10)
                             + ((long)L << 4) + t;
        *(uint2*)sp = *(uint2*)&s[0];
    }
}

// ---------------------------------------------------------------------------
// Q projection via EXACT int8 MFMA: NO LDS, NO BARRIERS, fragment-major
// contiguous 1KB-burst operand loads (verified r11). Pair-interleaved out.
// ---------------------------------------------------------------------------
__global__ __launch_bounds__(256, 4) void gemm_q_i8(
    const signed char* __restrict__ dig, const signed char* __restrict__ sg,
    const float* __restrict__ Bi, unsigned short* __restrict__ Yq)
{
    int tid  = threadIdx.x;
    int blk  = blockIdx.x;
    int low  = blk & 7, rest = blk >> 3;
    int bn   = (rest & 15) * 64;
    int bm   = (((rest >> 4) << 3) + low) * 64;
    int wave = tid >> 6, lane = tid & 63;
    int l15  = lane & 15, rg = lane >> 4;

    int rt  = (bm >> 4) + wave;            // this wave's 16-row tile
    int ct0 = bn >> 4;

    i32x4 acc[4][4];                        // [plane][j]  (16 rows x 64 cols)
    #pragma unroll
    for (int p = 0; p < 4; p++)
        #pragma unroll
        for (int j = 0; j < 4; j++) acc[p][j] = (i32x4)0;

    const signed char* ar = dig + ((size_t)rt << 16) + (lane << 4);
    const signed char* br = sg + ((size_t)ct0 << 14) + (lane << 4);

    i32x4 aA[4], bA[4], aB[4], bB[4];
    #pragma unroll
    for (int p = 0; p < 4; p++) aA[p] = *(const i32x4*)(ar + (p << 10));
    #pragma unroll
    for (int j = 0; j < 4; j++) bA[j] = *(const i32x4*)(br + (j << 14));

    #pragma unroll
    for (int kk = 0; kk < 8; kk++) {
        #pragma unroll
        for (int p = 0; p < 4; p++) aB[p] = *(const i32x4*)(ar + 4096 + (p << 10));
        #pragma unroll
        for (int j = 0; j < 4; j++) bB[j] = *(const i32x4*)(br + 1024 + (j << 14));
        #pragma unroll
        for (int p = 0; p < 4; p++)
            #pragma unroll
            for (int j = 0; j < 4; j++)
                acc[p][j] = __builtin_amdgcn_mfma_i32_16x16x64_i8(
                    aA[p], bA[j], acc[p][j], 0, 0, 0);
        if (kk < 7) {
            #pragma unroll
            for (int p = 0; p < 4; p++) aA[p] = *(const i32x4*)(ar + 8192 + (p << 10));
            #pragma unroll
            for (int j = 0; j < 4; j++) bA[j] = *(const i32x4*)(br + 2048 + (j << 14));
        }
        #pragma unroll
        for (int p = 0; p < 4; p++)
            #pragma unroll
            for (int j = 0; j < 4; j++)
                acc[p][j] = __builtin_amdgcn_mfma_i32_16x16x64_i8(
                    aB[p], bB[j], acc[p][j], 0, 0, 0);
        ar += 8192; br += 2048;
    }

    // ---- fused normq epilogue (in registers) ----
    int hh   = bn >> 6;
    int keep = KEEPC[hh];
    float bvj[4];
    #pragma unroll
    for (int j = 0; j < 4; j++) bvj[j] = Bi[bn + j * 16 + l15];

    float xv[4][4];
    #pragma unroll
    for (int j = 0; j < 4; j++)
        #pragma unroll
        for (int r = 0; r < 4; r++) {
            long t = (long)acc[0][j][r]
                   + ((long)acc[1][j][r] << 8)
                   + ((long)acc[2][j][r] << 16)
                   + ((long)acc[3][j][r] << 24);
            xv[j][r] = (float)((double)t * (1.0 / 8388608.0)) + bvj[j];
        }

    unsigned int shiftv = (unsigned int)(rg & 1) * 16;
    #pragma unroll
    for (int r = 0; r < 4; r++) {
        float ss = xv[0][r] * xv[0][r] + xv[1][r] * xv[1][r]
                 + xv[2][r] * xv[2][r] + xv[3][r] * xv[3][r];
        ss += __shfl_xor(ss, 1); ss += __shfl_xor(ss, 2);
        ss += __shfl_xor(ss, 4); ss += __shfl_xor(ss, 8);
        float rms = sqrtf(ss * (1.0f / 64.0f));

        float xn[4]; unsigned int ai[4];
        #pragma unroll
        for (int j = 0; j < 4; j++) {
            xn[j] = xv[j][r] / (rms + 1e-6f);
            ai[j] = __float_as_uint(fabsf(xn[j]));
        }

        unsigned int th = 0;
        for (int bit = 30; bit >= 0; --bit) {
            unsigned int cand = th | (1u << bit);
            int cnt = 0;
            #pragma unroll
            for (int j = 0; j < 4; j++) {
                unsigned long long bl = __ballot(ai[j] >= cand);
                unsigned int half = (rg & 2) ? (unsigned int)(bl >> 32)
                                             : (unsigned int)bl;
                cnt += __popc((half >> shiftv) & 0xFFFFu);
            }
            if (cnt >= keep) th = cand;
        }

        int row = bm + wave * 16 + rg * 4 + r;
        int bb = row >> 10, tt = row & 1023;
        unsigned int* qp32 = (unsigned int*)(Yq
            + (((size_t)(bb * NHEAD + hh)) * T_SEQ + tt) * 128);
        #pragma unroll
        for (int j = 0; j < 4; j++) {
            float o = (ai[j] < th) ? 0.f : xn[j];
            unsigned short hi = f2bf(o);
            unsigned short lo = f2bf(o - bf2f(hi));
            qp32[j * 16 + l15] = (unsigned int)hi | ((unsigned int)lo << 16);
        }
    }
}

// ---------------------------------------------------------------------------
// Merged K+V projection: LDS-staged + pre-split A + register prefetch
// (verified r12: dropped kv out of the top-5).
// ---------------------------------------------------------------------------
#define GLDK 72

__global__ __launch_bounds__(256, 2) void gemm_kv(
    const unsigned short* __restrict__ xhg, const unsigned short* __restrict__ xlg,
    const unsigned short* __restrict__ kwh, const unsigned short* __restrict__ kwl,
    const float* __restrict__ kb,
    const unsigned short* __restrict__ vwb, const float* __restrict__ vb,
    unsigned short* __restrict__ Yk, unsigned short* __restrict__ Yv)
{
    __shared__ unsigned short Ah[128 * GLDK];
    __shared__ unsigned short Al[128 * GLDK];
    __shared__ unsigned short Whs[128 * GLDK];
    __shared__ unsigned short Wls[128 * GLDK];

    int tid  = threadIdx.x;
    int blk  = blockIdx.x;
    int z    = blk >> 8;               // 0 = k, 1 = v
    int split = (z == 0);
    int inner = blk & 255;
    int low  = inner & 7, rest = inner >> 3;
    int bn   = (rest & 7) * 128;
    int bm   = (((rest >> 3) << 3) + low) * 128;
    const unsigned short* Wh = split ? kwh : vwb;
    const unsigned short* Wl = split ? kwl : vwb;
    const float*          Bi = split ? kb : vb;

    int wave = tid >> 6, lane = tid & 63;
    int l15  = lane & 15, q4 = lane >> 4;
    int wm   = (wave >> 1) * 64, wn = (wave & 1) * 64;
    int srow = tid >> 1;
    int scol = (tid & 1) * 32;

    f32x4 acc[4][4];
    #pragma unroll
    for (int i = 0; i < 4; i++)
        #pragma unroll
        for (int j = 0; j < 4; j++) acc[i][j] = (f32x4)0.f;

    const unsigned short* ahp = xhg + (size_t)(bm + srow) * D_MODEL + scol;
    const unsigned short* alp = xlg + (size_t)(bm + srow) * D_MODEL + scol;
    const unsigned short* whp = Wh + (size_t)(bn + srow) * D_MODEL + scol;
    const unsigned short* wlp = Wl + (size_t)(bn + srow) * D_MODEL + scol;

    // preload k0 = 0
    uint4 a0, a1, a2, a3, g0, g1, g2, g3;
    uint4 w0, w1, w2, w3, x0, x1, x2, x3;
    a0 = *(const uint4*)(ahp + 0);  a1 = *(const uint4*)(ahp + 8);
    a2 = *(const uint4*)(ahp + 16); a3 = *(const uint4*)(ahp + 24);
    w0 = *(const uint4*)(whp + 0);  w1 = *(const uint4*)(whp + 8);
    w2 = *(const uint4*)(whp + 16); w3 = *(const uint4*)(whp + 24);
    if (split) {
        g0 = *(const uint4*)(alp + 0);  g1 = *(const uint4*)(alp + 8);
        g2 = *(const uint4*)(alp + 16); g3 = *(const uint4*)(alp + 24);
        x0 = *(const uint4*)(wlp + 0);  x1 = *(const uint4*)(wlp + 8);
        x2 = *(const uint4*)(wlp + 16); x3 = *(const uint4*)(wlp + 24);
    }

    for (int k0 = 0; k0 < D_MODEL; k0 += 64) {
        __syncthreads();
        unsigned short* as = &Ah[srow * GLDK + scol];
        *(uint4*)(as + 0) = a0; *(uint4*)(as + 8)  = a1;
        *(uint4*)(as + 16) = a2; *(uint4*)(as + 24) = a3;
        unsigned short* ws = &Whs[srow * GLDK + scol];
        *(uint4*)(ws + 0) = w0; *(uint4*)(ws + 8)  = w1;
        *(uint4*)(ws + 16) = w2; *(uint4*)(ws + 24) = w3;
        if (split) {
            unsigned short* als = &Al[srow * GLDK + scol];
            *(uint4*)(als + 0) = g0; *(uint4*)(als + 8)  = g1;
            *(uint4*)(als + 16) = g2; *(uint4*)(als + 24) = g3;
            unsigned short* wl2 = &Wls[srow * GLDK + scol];
            *(uint4*)(wl2 + 0) = x0; *(uint4*)(wl2 + 8)  = x1;
            *(uint4*)(wl2 + 16) = x2; *(uint4*)(wl2 + 24) = x3;
        }
        __syncthreads();

        // issue NEXT iteration's loads (latency hides under the MFMA phase)
        if (k0 + 64 < D_MODEL) {
            ahp += 64; alp += 64; whp += 64; wlp += 64;
            a0 = *(const uint4*)(ahp + 0);  a1 = *(const uint4*)(ahp + 8);
            a2 = *(const uint4*)(ahp + 16); a3 = *(const uint4*)(ahp + 24);
            w0 = *(const uint4*)(whp + 0);  w1 = *(const uint4*)(whp + 8);
            w2 = *(const uint4*)(whp + 16); w3 = *(const uint4*)(whp + 24);
            if (split) {
                g0 = *(const uint4*)(alp + 0);  g1 = *(const uint4*)(alp + 8);
                g2 = *(const uint4*)(alp + 16); g3 = *(const uint4*)(alp + 24);
                x0 = *(const uint4*)(wlp + 0);  x1 = *(const uint4*)(wlp + 8);
                x2 = *(const uint4*)(wlp + 16); x3 = *(const uint4*)(wlp + 24);
            }
        }

        #pragma unroll
        for (int kc = 0; kc < 64; kc += 32) {
            bh8 ahf[4], whf[4];
            #pragma unroll
            for (int i = 0; i < 4; i++)
                ahf[i] = *(bh8*)&Ah[(wm + i * 16 + l15) * GLDK + kc + q4 * 8];
            #pragma unroll
            for (int j = 0; j < 4; j++)
                whf[j] = *(bh8*)&Whs[(wn + j * 16 + l15) * GLDK + kc + q4 * 8];
            #pragma unroll
            for (int i = 0; i < 4; i++)
                #pragma unroll
                for (int j = 0; j < 4; j++)
                    acc[i][j] = __builtin_amdgcn_mfma_f32_16x16x32_bf16(ahf[i], whf[j], acc[i][j], 0, 0, 0);
            if (split) {
                bh8 alf[4], wlf[4];
                #pragma unroll
                for (int i = 0; i < 4; i++)
                    alf[i] = *(bh8*)&Al[(wm + i * 16 + l15) * GLDK + kc + q4 * 8];
                #pragma unroll
                for (int j = 0; j < 4; j++)
                    wlf[j] = *(bh8*)&Wls[(wn + j * 16 + l15) * GLDK + kc + q4 * 8];
                #pragma unroll
                for (int i = 0; i < 4; i++)
                    #pragma unroll
                    for (int j = 0; j < 4; j++) {
                        acc[i][j] = __builtin_amdgcn_mfma_f32_16x16x32_bf16(ahf[i], wlf[j], acc[i][j], 0, 0, 0);
                        acc[i][j] = __builtin_amdgcn_mfma_f32_16x16x32_bf16(alf[i], whf[j], acc[i][j], 0, 0, 0);
                    }
            }
        }
    }

    if (split) {
        int hh = (bn + wn) >> 6;
        float bv[4];
        #pragma unroll
        for (int j = 0; j < 4; j++) bv[j] = Bi[bn + wn + j * 16 + l15];
        #pragma unroll
        for (int i = 0; i < 4; i++) {
            #pragma unroll
            for (int r = 0; r < 4; r++) {
                int row = bm + wm + i * 16 + q4 * 4 + r;
                int bb = row >> 10, tt = row & 1023;
                float vv[4]; float ss = 0.f;
                #pragma unroll
                for (int j = 0; j < 4; j++) {
                    vv[j] = acc[i][j][r] + bv[j];
                    ss += vv[j] * vv[j];
                }
                ss += __shfl_xor(ss, 1); ss += __shfl_xor(ss, 2);
                ss += __shfl_xor(ss, 4); ss += __shfl_xor(ss, 8);
                float rms = sqrtf(ss * (1.0f / 64.0f));
                unsigned short* kp = Yk + (((size_t)(bb * NHEAD + hh)) * T_SEQ + tt) * 128;
                #pragma unroll
                for (int j = 0; j < 4; j++) {
                    float xn = vv[j] / (rms + 1e-6f);
                    unsigned short hi = f2bf(xn);
                    unsigned short lo = f2bf(xn - bf2f(hi));
                    kp[j * 16 + l15]      = hi;
                    kp[64 + j * 16 + l15] = lo;
                }
            }
        }
    } else {
        #pragma unroll
        for (int j = 0; j < 4; j++) {
            int col = bn + wn + j * 16 + l15;
            int hh = col >> 6, dd = col & 63;
            float bvv = Bi[col];
            #pragma unroll
            for (int i = 0; i < 4; i++) {
                int row0 = bm + wm + i * 16 + q4 * 4;
                int bb = row0 >> 10, tt = row0 & 1023;
                uint2 u;
                u.x = (unsigned int)f2bf(acc[i][j][0] + bvv) | ((unsigned int)f2bf(acc[i][j][1] + bvv) << 16);
                u.y = (unsigned int)f2bf(acc[i][j][2] + bvv) | ((unsigned int)f2bf(acc[i][j][3] + bvv) << 16);
                *(uint2*)(Yv + ((size_t)(bb * NHEAD + hh) * HDIM + dd) * T_SEQ + tt) = u;
            }
        }
    }
}

// ---------------------------------------------------------------------------
// MFMA flash attention (r12 verified version: loads at loop top).
// Q pair-interleaved, unpack via v_perm_b32 (verified).
// ---------------------------------------------------------------------------
#define KST 72

__global__ __launch_bounds__(256, 4) void attn_kernel(
    const unsigned short* __restrict__ Qsg,   // [row][64 uints] = (hi,lo) pairs
    const unsigned short* __restrict__ Ksg,   // [row][128] = 64 hi | 64 lo
    const unsigned short* __restrict__ Vtg,   // [(bh)*64+d][1024] bf16
    unsigned short* __restrict__ Ctx, double* __restrict__ He)
{
    __shared__ unsigned short Kh[64 * KST];
    __shared__ unsigned short Kl[64 * KST];
    __shared__ unsigned short Vt[64 * KST];
    __shared__ unsigned short Ps[4][16 * KST];

    int tid = threadIdx.x;
    int blk = blockIdx.x;
    int low = blk & 7, rest = blk >> 3;
    int qt  = 15 - (rest & 15);               // heavy blocks first
    int r2  = rest >> 4;
    int h   = (r2 & 1) * 8 + low;
    int b   = r2 >> 1;
    int bh = b * NHEAD + h;
    size_t rbase = (size_t)bh * T_SEQ;

    int wave = tid >> 6, lane = tid & 63;
    int l15 = lane & 15, rg = lane >> 4;
    int srow = tid >> 2;
    int scol = (tid & 3) * 16;

    int qrow = qt * 64 + wave * 16 + l15;

    bh8 qf[2][2];
    {
        const unsigned int* qp32 = (const unsigned int*)(Qsg + (rbase + qrow) * 128);
        uint4 a = *(const uint4*)(qp32 + rg * 8);
        uint4 c = *(const uint4*)(qp32 + rg * 8 + 4);
        uint4 d = *(const uint4*)(qp32 + 32 + rg * 8);
        uint4 e = *(const uint4*)(qp32 + 32 + rg * 8 + 4);
        unsigned int hv[4], lv[4];
        hv[0] = __builtin_amdgcn_perm(a.y, a.x, 0x05040100u);
        hv[1] = __builtin_amdgcn_perm(a.w, a.z, 0x05040100u);
        hv[2] = __builtin_amdgcn_perm(c.y, c.x, 0x05040100u);
        hv[3] = __builtin_amdgcn_perm(c.w, c.z, 0x05040100u);
        lv[0] = __builtin_amdgcn_perm(a.y, a.x, 0x07060302u);
        lv[1] = __builtin_amdgcn_perm(a.w, a.z, 0x07060302u);
        lv[2] = __builtin_amdgcn_perm(c.y, c.x, 0x07060302u);
        lv[3] = __builtin_amdgcn_perm(c.w, c.z, 0x07060302u);
        qf[0][0] = *(bh8*)hv;                 // hi, cols rg*8..+7
        qf[1][0] = *(bh8*)lv;                 // lo, cols rg*8..+7
        hv[0] = __builtin_amdgcn_perm(d.y, d.x, 0x05040100u);
        hv[1] = __builtin_amdgcn_perm(d.w, d.z, 0x05040100u);
        hv[2] = __builtin_amdgcn_perm(e.y, e.x, 0x05040100u);
        hv[3] = __builtin_amdgcn_perm(e.w, e.z, 0x05040100u);
        lv[0] = __builtin_amdgcn_perm(d.y, d.x, 0x07060302u);
        lv[1] = __builtin_amdgcn_perm(d.w, d.z, 0x07060302u);
        lv[2] = __builtin_amdgcn_perm(e.y, e.x, 0x07060302u);
        lv[3] = __builtin_amdgcn_perm(e.w, e.z, 0x07060302u);
        qf[0][1] = *(bh8*)hv;                 // hi, cols 32+rg*8..+7
        qf[1][1] = *(bh8*)lv;                 // lo, cols 32+rg*8..+7
    }

    float m = -1e30f, l = 0.f, s2 = 0.f;
    f32x4 o[4];
    #pragma unroll
    for (int n = 0; n < 4; n++) o[n] = (f32x4)0.f;

    unsigned short* myPs = &Ps[wave][0];
    const unsigned short* vbase = Vtg + (size_t)bh * HDIM * T_SEQ;

    for (int kt = 0; kt <= qt; ++kt) {
        const unsigned short* krow = Ksg + (rbase + kt * 64 + srow) * 128;
        uint4 kh0 = *(const uint4*)(krow + scol);
        uint4 kh1 = *(const uint4*)(krow + scol + 8);
        uint4 kl0 = *(const uint4*)(krow + 64 + scol);
        uint4 kl1 = *(const uint4*)(krow + 64 + scol + 8);
        const unsigned short* vrow = vbase + (size_t)srow * T_SEQ + kt * 64 + scol;
        uint4 vv0 = *(const uint4*)(vrow);
        uint4 vv1 = *(const uint4*)(vrow + 8);

        __syncthreads();
        *(uint4*)&Kh[srow * KST + scol]     = kh0;
        *(uint4*)&Kh[srow * KST + scol + 8] = kh1;
        *(uint4*)&Kl[srow * KST + scol]     = kl0;
        *(uint4*)&Kl[srow * KST + scol + 8] = kl1;
        *(uint4*)&Vt[srow * KST + scol]     = vv0;
        *(uint4*)&Vt[srow * KST + scol + 8] = vv1;
        __syncthreads();

        f32x4 s[4];
        #pragma unroll
        for (int n = 0; n < 4; n++) s[n] = (f32x4)0.f;
        #pragma unroll
        for (int n = 0; n < 4; n++) {
            const unsigned short* kr = &Kh[(n * 16 + l15) * KST + rg * 8];
            const unsigned short* lr = &Kl[(n * 16 + l15) * KST + rg * 8];
            bh8 ah0 = *(const bh8*)(kr);
            bh8 ah1 = *(const bh8*)(kr + 32);
            bh8 al0 = *(const bh8*)(lr);
            bh8 al1 = *(const bh8*)(lr + 32);
            s[n] = __builtin_amdgcn_mfma_f32_16x16x32_bf16(ah0, qf[0][0], s[n], 0, 0, 0);
            s[n] = __builtin_amdgcn_mfma_f32_16x16x32_bf16(ah1, qf[0][1], s[n], 0, 0, 0);
            s[n] = __builtin_amdgcn_mfma_f32_16x16x32_bf16(ah0, qf[1][0], s[n], 0, 0, 0);
            s[n] = __builtin_amdgcn_mfma_f32_16x16x32_bf16(ah1, qf[1][1], s[n], 0, 0, 0);
            s[n] = __builtin_amdgcn_mfma_f32_16x16x32_bf16(al0, qf[0][0], s[n], 0, 0, 0);
            s[n] = __builtin_amdgcn_mfma_f32_16x16x32_bf16(al1, qf[0][1], s[n], 0, 0, 0);
        }

        if (kt == qt) {
            #pragma unroll
            for (int n = 0; n < 4; n++)
                #pragma unroll
                for (int e2 = 0; e2 < 4; e2++)
                    if (n * 16 + rg * 4 + e2 > wave * 16 + l15) s[n][e2] = -1e30f;
        }

        float mx = -1e30f;
        #pragma unroll
        for (int n = 0; n < 4; n++)
            #pragma unroll
            for (int e2 = 0; e2 < 4; e2++) mx = fmaxf(mx, s[n][e2]);
        mx = fmaxf(mx, __shfl_xor(mx, 16));
        mx = fmaxf(mx, __shfl_xor(mx, 32));
        float mn = fmaxf(m, mx);
        float alpha = __expf(m - mn);
        m = mn;
        float rs = 0.f, rs2 = 0.f;
        #pragma unroll
        for (int n = 0; n < 4; n++)
            #pragma unroll
            for (int e2 = 0; e2 < 4; e2++) {
                float pv = __expf(s[n][e2] - mn);
                s[n][e2] = pv;
                rs += pv; rs2 += pv * pv;
            }
        rs  += __shfl_xor(rs, 16);  rs  += __shfl_xor(rs, 32);
        rs2 += __shfl_xor(rs2, 16); rs2 += __shfl_xor(rs2, 32);
        l  = l * alpha + rs;
        s2 = s2 * alpha * alpha + rs2;

        #pragma unroll
        for (int n = 0; n < 4; n++) {
            uint2 u;
            u.x = (unsigned int)f2bf(s[n][0]) | ((unsigned int)f2bf(s[n][1]) << 16);
            u.y = (unsigned int)f2bf(s[n][2]) | ((unsigned int)f2bf(s[n][3]) << 16);
            *(uint2*)&myPs[l15 * KST + n * 16 + rg * 4] = u;
        }
        bh8 pf0 = *(bh8*)&myPs[l15 * KST + rg * 8];
        bh8 pf1 = *(bh8*)&myPs[l15 * KST + 32 + rg * 8];

        #pragma unroll
        for (int n = 0; n < 4; n++) {
            o[n] *= alpha;
            const unsigned short* vr = &Vt[(n * 16 + l15) * KST + rg * 8];
            bh8 v0 = *(const bh8*)(vr);
            bh8 v1 = *(const bh8*)(vr + 32);
            o[n] = __builtin_amdgcn_mfma_f32_16x16x32_bf16(v0, pf0, o[n], 0, 0, 0);
            o[n] = __builtin_amdgcn_mfma_f32_16x16x32_bf16(v1, pf1, o[n], 0, 0, 0);
        }
    }

    float linv = 1.f / l;
    float en = (rg == 0) ? s2 * linv * linv : 0.f;
    en += __shfl_xor(en, 1); en += __shfl_xor(en, 2);
    en += __shfl_xor(en, 4); en += __shfl_xor(en, 8);
    if (lane == 0) atomicAdd(&He[bh], (double)en);

    unsigned short* cp = Ctx + ((size_t)b * T_SEQ + qrow) * D_MODEL + h * HDIM;
    #pragma unroll
    for (int n = 0; n < 4; n++) {
        uint2 u;
        u.x = (unsigned int)f2bf(o[n][0] * linv) | ((unsigned int)f2bf(o[n][1] * linv) << 16);
        u.y = (unsigned int)f2bf(o[n][2] * linv) | ((unsigned int)f2bf(o[n][3] * linv) << 16);
        *(uint2*)(cp + n * 16 + rg * 4) = u;
    }
}

// ---------------------------------------------------------------------------
// Out-projection with FUSED head selection + UNIFORM MASK-SKIP (verified).
// ---------------------------------------------------------------------------
__global__ __launch_bounds__(256, 2) void gemm_obf(
    const unsigned short* __restrict__ A, const unsigned short* __restrict__ W,
    const float* __restrict__ Bi, float* __restrict__ Y,
    const double* __restrict__ He)
{
    __shared__ unsigned short As[128 * GLDK];
    __shared__ unsigned short Ws[128 * GLDK];
    __shared__ double hs[34];       // [0..15] e, [16..31] p/terms, [32] sum
    __shared__ float maskS[NHEAD];

    int tid  = threadIdx.x;
    int blk  = blockIdx.x;
    int low  = blk & 7, rest = blk >> 3;
    int bn   = (rest & 7) * 128;
    int bm   = (((rest >> 3) << 3) + low) * 128;
    int batch = bm >> 10;

    // ---- fused headsel (per-block, deterministic)
    if (tid < NHEAD) hs[tid] = He[batch * NHEAD + tid] * (1.0 / (1024.0 * 1024.0));
    __syncthreads();
    if (tid < NHEAD) {
        double mx = hs[0];
        for (int h2 = 1; h2 < NHEAD; h2++) mx = fmax(mx, hs[h2]);
        hs[NHEAD + tid] = exp(hs[tid] - mx);
    }
    __syncthreads();
    if (tid == 0) {
        double s = 0.0;
        for (int h2 = 0; h2 < NHEAD; h2++) s += hs[NHEAD + h2];
        hs[32] = s;
    }
    __syncthreads();
    if (tid < NHEAD) {
        double ph = hs[NHEAD + tid] / hs[32];
        hs[NHEAD + tid] = ph * log(ph + 1e-9);
    }
    __syncthreads();
    if (tid == 0) {
        double ent = 0.0;
        for (int h2 = 0; h2 < NHEAD; h2++) ent -= hs[NHEAD + h2];
        double entn = ent / log(16.0);
        entn = fmin(fmax(entn, 0.0), 1.0);
        int keep = (int)rint(2.0 + entn * 4.0);
        if (keep < 1) keep = 1;
        if (keep > NHEAD) keep = NHEAD;
        double srt[NHEAD];
        for (int h2 = 0; h2 < NHEAD; h2++) srt[h2] = hs[h2];
        for (int i = 1; i < NHEAD; i++) {
            double v = srt[i]; int j = i - 1;
            while (j >= 0 && srt[j] < v) { srt[j + 1] = srt[j]; j--; }
            srt[j + 1] = v;
        }
        double th = srt[keep - 1];
        for (int h2 = 0; h2 < NHEAD; h2++)
            maskS[h2] = (hs[h2] >= th) ? 1.0f : 0.0f;
    }
    __syncthreads();

    int wave = tid >> 6, lane = tid & 63;
    int l15  = lane & 15, q4 = lane >> 4;
    int wm   = (wave >> 1) * 64, wn = (wave & 1) * 64;
    int srow = tid >> 1;
    int scol = (tid & 1) * 32;

    f32x4 acc[4][4];
    #pragma unroll
    for (int i = 0; i < 4; i++)
        #pragma unroll
        for (int j = 0; j < 4; j++) acc[i][j] = (f32x4)0.f;

    const unsigned short* ap = A + (size_t)(bm + srow) * D_MODEL + scol;
    const unsigned short* wp = W + (size_t)(bn + srow) * D_MODEL + scol;

    for (int k0 = 0; k0 < D_MODEL; k0 += 64) {
        // UNIFORM skip: pruned head slab contributes exactly 0
        if (maskS[k0 >> 6] == 0.f) { ap += 64; wp += 64; continue; }

        uint4 a0 = *(const uint4*)(ap + 0),  a1 = *(const uint4*)(ap + 8);
        uint4 a2 = *(const uint4*)(ap + 16), a3 = *(const uint4*)(ap + 24);
        uint4 w0 = *(const uint4*)(wp + 0),  w1 = *(const uint4*)(wp + 8);
        uint4 w2 = *(const uint4*)(wp + 16), w3 = *(const uint4*)(wp + 24);
        ap += 64; wp += 64;
        __syncthreads();
        unsigned short* as = &As[srow * GLDK + scol];
        *(uint4*)(as + 0) = a0; *(uint4*)(as + 8)  = a1;
        *(uint4*)(as + 16) = a2; *(uint4*)(as + 24) = a3;
        unsigned short* ws = &Ws[srow * GLDK + scol];
        *(uint4*)(ws + 0) = w0; *(uint4*)(ws + 8)  = w1;
        *(uint4*)(ws + 16) = w2; *(uint4*)(ws + 24) = w3;
        __syncthreads();

        #pragma unroll
        for (int kc = 0; kc < 64; kc += 32) {
            bh8 af[4], wf[4];
            #pragma unroll
            for (int i = 0; i < 4; i++)
                af[i] = *(bh8*)&As[(wm + i * 16 + l15) * GLDK + kc + q4 * 8];
            #pragma unroll
            for (int j = 0; j < 4; j++)
                wf[j] = *(bh8*)&Ws[(wn + j * 16 + l15) * GLDK + kc + q4 * 8];
            #pragma unroll
            for (int i = 0; i < 4; i++)
                #pragma unroll
                for (int j = 0; j < 4; j++)
                    acc[i][j] = __builtin_amdgcn_mfma_f32_16x16x32_bf16(af[i], wf[j], acc[i][j], 0, 0, 0);
        }
    }

    #pragma unroll
    for (int j = 0; j < 4; j++) {
        int col = bn + wn + j * 16 + l15;
        float bv = Bi[col];
        #pragma unroll
        for (int i = 0; i < 4; i++) {
            int row = bm + wm + i * 16 + q4 * 4;
            #pragma unroll
            for (int r = 0; r < 4; r++)
                Y[(size_t)(row + r) * D_MODEL + col] = acc[i][j][r] + bv;
        }
    }
}

// ---------------------------------------------------------------------------
extern "C" void kernel_launch(void* const* d_in, const int* in_sizes, int n_in,
                              void* d_out, int out_size, void* d_ws, size_t ws_size,
                              hipStream_t stream)
{
    (void)in_sizes; (void)n_in; (void)out_size; (void)ws_size;
    const float* x  = (const float*)d_in[0];
    const float* qw = (const float*)d_in[1];
    const float* qb = (const float*)d_in[2];
    const float* kw = (const float*)d_in[3];
    const float* kb = (const float*)d_in[4];
    const float* vw = (const float*)d_in[5];
    const float* vb = (const float*)d_in[6];
    const float* ow = (const float*)d_in[7];
    const float* ob = (const float*)d_in[8];
    float* out = (float*)d_out;

    // Memory map (sequential pipeline — dig overlay safe):
    //   0-16   qbf (uint-pair rows [(b*16+h)*1024+t][64]: (hi_c,lo_c))
    //  16-32   kbf  (norm-split bf16: 65536 rows x 256 B = 16 MB)
    //  32-40   vt   (V^T bf16, 8 MB)
    //  40-48   ctxb (bf16, 8 MB)
    //  32-48   dig  (16 MB, FRAGMENT-MAJOR; OVERLAYS vt+ctxb; fully consumed
    //               by gemm_q_i8 before gemm_kv writes vt / attn writes ctxb)
    //  48-56   kwh, kwl, vwb, owb (2 MB each)
    //  56-57   sg (fragment-major)
    //  57-58   he (512 B)
    //  58-66   xh (bf16 hi plane of x, row-major, 8 MB)
    //  66-74   xl (bf16 lo plane of x, row-major, 8 MB)
    char* base = (char*)d_ws;
    const size_t MB = (size_t)1024 * 1024;
    unsigned short* qbf  = (unsigned short*)(base);
    unsigned short* kbf  = (unsigned short*)(base + 16 * MB);
    unsigned short* vt   = (unsigned short*)(base + 32 * MB);
    unsigned short* ctxb = (unsigned short*)(base + 40 * MB);
    signed char*    dig  = (signed char*)(base + 32 * MB);
    unsigned short* kwh  = (unsigned short*)(base + 48 * MB);
    unsigned short* kwl  = (unsigned short*)(base + 50 * MB);
    unsigned short* vwb  = (unsigned short*)(base + 52 * MB);
    unsigned short* owb  = (unsigned short*)(base + 54 * MB);
    signed char*    sg   = (signed char*)(base + 56 * MB);
    double*         he   = (double*)(base + 57 * MB);
    unsigned short* xh   = (unsigned short*)(base + 58 * MB);
    unsigned short* xl   = (unsigned short*)(base + 66 * MB);

    hipMemsetAsync(he, 0, 64 * sizeof(double), stream);

    // weights cast + x digitize (fragment-major) + x hi/lo split + qw sign
    cast_prep<<<4096, 256, 0, stream>>>(kw, kwh, kwl, vw, vwb, ow, owb,
                                        x, dig, xh, xl, qw, sg);
    // q projection: barrier-free, contiguous fragment loads + fused RMS/top-k
    gemm_q_i8<<<1024, 256, 0, stream>>>(dig, sg, qb, qbf);
    // k + v projection: LDS-staged, pre-split A + register prefetch
    gemm_kv<<<512, 256, 0, stream>>>(xh, xl, kwh, kwl, kb, vwb, vb, kbf, vt);
    attn_kernel<<<1024, 256, 0, stream>>>(qbf, kbf, vt, ctxb, he);
    // out-projection with fused head selection + mask-skip
    gemm_obf<<<256, 256, 0, stream>>>(ctxb, owb, ob, out, he);
}

// Round 16
// 239.925 us; speedup vs baseline: 1.0687x; 1.0687x over previous
//
#include <hip/hip_runtime.h>
#include <math.h>

#define D_MODEL 1024
#define T_SEQ   1024
#define BATCH   4
#define NHEAD   16
#define HDIM    64

// keep counts: trunc(linspace(0.35,0.15,16)*64), min 1
__constant__ int KEEPC[16] = {22,21,20,19,18,18,17,16,15,14,13,13,12,11,10,9};

typedef short bh8  __attribute__((ext_vector_type(8)));
typedef float f32x4 __attribute__((ext_vector_type(4)));
typedef int   i32x4 __attribute__((ext_vector_type(4)));

__device__ __forceinline__ unsigned short f2bf(float f) {
    unsigned int u = __float_as_uint(f);
    return (unsigned short)((u + 0x7FFFu + ((u >> 16) & 1u)) >> 16);
}
__device__ __forceinline__ float bf2f(unsigned short h) {
    return __uint_as_float(((unsigned int)h) << 16);
}

// ---------------------------------------------------------------------------
// cast_prep:
//  kw -> (hi,lo) bf16; vw, ow -> bf16;
//  x  -> (a) base-256 digit planes FRAGMENT-MAJOR for gemm_q (verified r11);
//        (b) bf16 hi/lo planes xh/xl ROW-MAJOR for gemm_kv (verified r12);
//  qw -> sign int8 fragment-major.
// ---------------------------------------------------------------------------
__global__ void cast_prep(const float* __restrict__ kw,
                          unsigned short* __restrict__ kwh,
                          unsigned short* __restrict__ kwl,
                          const float* __restrict__ vw,
                          unsigned short* __restrict__ vwb,
                          const float* __restrict__ ow,
                          unsigned short* __restrict__ owb,
                          const float* __restrict__ x,
                          signed char* __restrict__ dig,
                          unsigned short* __restrict__ xh,
                          unsigned short* __restrict__ xl,
                          const float* __restrict__ qw,
                          signed char* __restrict__ sg)
{
    const int NS = (D_MODEL * D_MODEL) / 8;          // 131072
    const int NX = (BATCH * T_SEQ * D_MODEL) / 8;    // 524288
    int i = blockIdx.x * 256 + threadIdx.x;

    if (i < 3 * NS) {
        const float* src; unsigned short* dh; unsigned short* dl = nullptr;
        long off;
        if (i < NS)          { src = kw; dh = kwh; dl = kwl; off = i; }
        else if (i < 2 * NS) { src = vw; dh = vwb; off = i - NS; }
        else                 { src = ow; dh = owb; off = i - 2 * NS; }
        long e = off * 8;
        alignas(16) float fl[8];
        *(float4*)&fl[0] = *(const float4*)(src + e);
        *(float4*)&fl[4] = *(const float4*)(src + e + 4);
        uint4 hp, lp;
        unsigned int* hpw = (unsigned int*)&hp;
        unsigned int* lpw = (unsigned int*)&lp;
        #pragma unroll
        for (int c = 0; c < 4; c++) {
            unsigned short h0 = f2bf(fl[2 * c]), h1 = f2bf(fl[2 * c + 1]);
            hpw[c] = (unsigned int)h0 | ((unsigned int)h1 << 16);
            if (dl) {
                unsigned short l0 = f2bf(fl[2 * c] - bf2f(h0));
                unsigned short l1 = f2bf(fl[2 * c + 1] - bf2f(h1));
                lpw[c] = (unsigned int)l0 | ((unsigned int)l1 << 16);
            }
        }
        *(uint4*)(dh + e) = hp;
        if (dl) *(uint4*)(dl + e) = lp;
    } else if (i < 3 * NS + NX) {
        long e = (long)(i - 3 * NS) * 8;
        alignas(16) float f[8];
        *(float4*)&f[0] = *(const float4*)(x + e);
        *(float4*)&f[4] = *(const float4*)(x + e + 4);
        signed char d[4][8];
        #pragma unroll
        for (int c = 0; c < 8; c++) {
            int n = (int)rintf(f[c] * 8388608.0f);
            int d0 = (signed char)(n & 0xff); n = (n - d0) >> 8;
            int d1 = (signed char)(n & 0xff); n = (n - d1) >> 8;
            int d2 = (signed char)(n & 0xff); n = (n - d2) >> 8;
            d[0][c] = (signed char)d0; d[1][c] = (signed char)d1;
            d[2][c] = (signed char)d2; d[3][c] = (signed char)n;
        }
        // fragment-major: dig[rt][kstep][p][L][16], L = rg*16 + (row&15)
        long row = e >> 10;
        int  kk  = (int)(e & 1023);
        long rt  = row >> 4;
        int  l15r = (int)(row & 15);
        int  kstep = kk >> 6;
        int  rg2 = (kk >> 4) & 3;
        int  L = rg2 * 16 + l15r;
        int  t = kk & 15;                       // 0 or 8
        signed char* dp = dig + (rt << 16) + ((long)kstep << 12)
                              + ((long)L << 4) + t;
        #pragma unroll
        for (int p = 0; p < 4; p++)
            *(uint2*)(dp + (p << 10)) = *(uint2*)&d[p][0];
        // bf16 hi/lo planes (row-major) for gemm_kv
        uint4 hp, lp;
        unsigned int* hpw = (unsigned int*)&hp;
        unsigned int* lpw = (unsigned int*)&lp;
        #pragma unroll
        for (int c = 0; c < 4; c++) {
            unsigned short h0 = f2bf(f[2 * c]), h1 = f2bf(f[2 * c + 1]);
            hpw[c] = (unsigned int)h0 | ((unsigned int)h1 << 16);
            unsigned short l0 = f2bf(f[2 * c] - bf2f(h0));
            unsigned short l1 = f2bf(f[2 * c + 1] - bf2f(h1));
            lpw[c] = (unsigned int)l0 | ((unsigned int)l1 << 16);
        }
        *(uint4*)(xh + e) = hp;
        *(uint4*)(xl + e) = lp;
    } else if (i < 3 * NS + NX + NS) {
        long e = (long)(i - 3 * NS - NX) * 8;
        alignas(16) float f[8];
        *(float4*)&f[0] = *(const float4*)(qw + e);
        *(float4*)&f[4] = *(const float4*)(qw + e + 4);
        signed char s[8];
        #pragma unroll
        for (int c = 0; c < 8; c++)
            s[c] = (signed char)((f[c] > 0.f) - (f[c] < 0.f));
        // fragment-major: sg[ct][kstep][L][16], L = rg*16 + (col&15)
        long col = e >> 10;
        int  kk  = (int)(e & 1023);
        long ct  = col >> 4;
        int  l15c = (int)(col & 15);
        int  kstep = kk >> 6;
        int  rg2 = (kk >> 4) & 3;
        int  L = rg2 * 16 + l15c;
        int  t = kk & 15;
        signed char* sp = sg + (ct << 14) + ((long)kstep << 10)
                             + ((long)L << 4) + t;
        *(uint2*)sp = *(uint2*)&s[0];
    }
}

// ---------------------------------------------------------------------------
// Q projection via EXACT int8 MFMA: NO LDS, NO BARRIERS, fragment-major
// contiguous 1KB-burst operand loads (verified r11). Pair-interleaved out.
// ---------------------------------------------------------------------------
__global__ __launch_bounds__(256, 4) void gemm_q_i8(
    const signed char* __restrict__ dig, const signed char* __restrict__ sg,
    const float* __restrict__ Bi, unsigned short* __restrict__ Yq)
{
    int tid  = threadIdx.x;
    int blk  = blockIdx.x;
    int low  = blk & 7, rest = blk >> 3;
    int bn   = (rest & 15) * 64;
    int bm   = (((rest >> 4) << 3) + low) * 64;
    int wave = tid >> 6, lane = tid & 63;
    int l15  = lane & 15, rg = lane >> 4;

    int rt  = (bm >> 4) + wave;            // this wave's 16-row tile
    int ct0 = bn >> 4;

    i32x4 acc[4][4];                        // [plane][j]  (16 rows x 64 cols)
    #pragma unroll
    for (int p = 0; p < 4; p++)
        #pragma unroll
        for (int j = 0; j < 4; j++) acc[p][j] = (i32x4)0;

    const signed char* ar = dig + ((size_t)rt << 16) + (lane << 4);
    const signed char* br = sg + ((size_t)ct0 << 14) + (lane << 4);

    i32x4 aA[4], bA[4], aB[4], bB[4];
    #pragma unroll
    for (int p = 0; p < 4; p++) aA[p] = *(const i32x4*)(ar + (p << 10));
    #pragma unroll
    for (int j = 0; j < 4; j++) bA[j] = *(const i32x4*)(br + (j << 14));

    #pragma unroll
    for (int kk = 0; kk < 8; kk++) {
        #pragma unroll
        for (int p = 0; p < 4; p++) aB[p] = *(const i32x4*)(ar + 4096 + (p << 10));
        #pragma unroll
        for (int j = 0; j < 4; j++) bB[j] = *(const i32x4*)(br + 1024 + (j << 14));
        #pragma unroll
        for (int p = 0; p < 4; p++)
            #pragma unroll
            for (int j = 0; j < 4; j++)
                acc[p][j] = __builtin_amdgcn_mfma_i32_16x16x64_i8(
                    aA[p], bA[j], acc[p][j], 0, 0, 0);
        if (kk < 7) {
            #pragma unroll
            for (int p = 0; p < 4; p++) aA[p] = *(const i32x4*)(ar + 8192 + (p << 10));
            #pragma unroll
            for (int j = 0; j < 4; j++) bA[j] = *(const i32x4*)(br + 2048 + (j << 14));
        }
        #pragma unroll
        for (int p = 0; p < 4; p++)
            #pragma unroll
            for (int j = 0; j < 4; j++)
                acc[p][j] = __builtin_amdgcn_mfma_i32_16x16x64_i8(
                    aB[p], bB[j], acc[p][j], 0, 0, 0);
        ar += 8192; br += 2048;
    }

    // ---- fused normq epilogue (in registers) ----
    int hh   = bn >> 6;
    int keep = KEEPC[hh];
    float bvj[4];
    #pragma unroll
    for (int j = 0; j < 4; j++) bvj[j] = Bi[bn + j * 16 + l15];

    float xv[4][4];
    #pragma unroll
    for (int j = 0; j < 4; j++)
        #pragma unroll
        for (int r = 0; r < 4; r++) {
            long t = (long)acc[0][j][r]
                   + ((long)acc[1][j][r] << 8)
                   + ((long)acc[2][j][r] << 16)
                   + ((long)acc[3][j][r] << 24);
            xv[j][r] = (float)((double)t * (1.0 / 8388608.0)) + bvj[j];
        }

    unsigned int shiftv = (unsigned int)(rg & 1) * 16;
    #pragma unroll
    for (int r = 0; r < 4; r++) {
        float ss = xv[0][r] * xv[0][r] + xv[1][r] * xv[1][r]
                 + xv[2][r] * xv[2][r] + xv[3][r] * xv[3][r];
        ss += __shfl_xor(ss, 1); ss += __shfl_xor(ss, 2);
        ss += __shfl_xor(ss, 4); ss += __shfl_xor(ss, 8);
        float rms = sqrtf(ss * (1.0f / 64.0f));

        float xn[4]; unsigned int ai[4];
        #pragma unroll
        for (int j = 0; j < 4; j++) {
            xn[j] = xv[j][r] / (rms + 1e-6f);
            ai[j] = __float_as_uint(fabsf(xn[j]));
        }

        unsigned int th = 0;
        for (int bit = 30; bit >= 0; --bit) {
            unsigned int cand = th | (1u << bit);
            int cnt = 0;
            #pragma unroll
            for (int j = 0; j < 4; j++) {
                unsigned long long bl = __ballot(ai[j] >= cand);
                unsigned int half = (rg & 2) ? (unsigned int)(bl >> 32)
                                             : (unsigned int)bl;
                cnt += __popc((half >> shiftv) & 0xFFFFu);
            }
            if (cnt >= keep) th = cand;
        }

        int row = bm + wave * 16 + rg * 4 + r;
        int bb = row >> 10, tt = row & 1023;
        unsigned int* qp32 = (unsigned int*)(Yq
            + (((size_t)(bb * NHEAD + hh)) * T_SEQ + tt) * 128);
        #pragma unroll
        for (int j = 0; j < 4; j++) {
            float o = (ai[j] < th) ? 0.f : xn[j];
            unsigned short hi = f2bf(o);
            unsigned short lo = f2bf(o - bf2f(hi));
            qp32[j * 16 + l15] = (unsigned int)hi | ((unsigned int)lo << 16);
        }
    }
}

// ---------------------------------------------------------------------------
// Merged K+V projection: LDS-staged + pre-split A + register prefetch
// (verified r12: dropped kv out of the top-5).
// ---------------------------------------------------------------------------
#define GLDK 72

__global__ __launch_bounds__(256, 2) void gemm_kv(
    const unsigned short* __restrict__ xhg, const unsigned short* __restrict__ xlg,
    const unsigned short* __restrict__ kwh, const unsigned short* __restrict__ kwl,
    const float* __restrict__ kb,
    const unsigned short* __restrict__ vwb, const float* __restrict__ vb,
    unsigned short* __restrict__ Yk, unsigned short* __restrict__ Yv)
{
    __shared__ unsigned short Ah[128 * GLDK];
    __shared__ unsigned short Al[128 * GLDK];
    __shared__ unsigned short Whs[128 * GLDK];
    __shared__ unsigned short Wls[128 * GLDK];

    int tid  = threadIdx.x;
    int blk  = blockIdx.x;
    int z    = blk >> 8;               // 0 = k, 1 = v
    int split = (z == 0);
    int inner = blk & 255;
    int low  = inner & 7, rest = inner >> 3;
    int bn   = (rest & 7) * 128;
    int bm   = (((rest >> 3) << 3) + low) * 128;
    const unsigned short* Wh = split ? kwh : vwb;
    const unsigned short* Wl = split ? kwl : vwb;
    const float*          Bi = split ? kb : vb;

    int wave = tid >> 6, lane = tid & 63;
    int l15  = lane & 15, q4 = lane >> 4;
    int wm   = (wave >> 1) * 64, wn = (wave & 1) * 64;
    int srow = tid >> 1;
    int scol = (tid & 1) * 32;

    f32x4 acc[4][4];
    #pragma unroll
    for (int i = 0; i < 4; i++)
        #pragma unroll
        for (int j = 0; j < 4; j++) acc[i][j] = (f32x4)0.f;

    const unsigned short* ahp = xhg + (size_t)(bm + srow) * D_MODEL + scol;
    const unsigned short* alp = xlg + (size_t)(bm + srow) * D_MODEL + scol;
    const unsigned short* whp = Wh + (size_t)(bn + srow) * D_MODEL + scol;
    const unsigned short* wlp = Wl + (size_t)(bn + srow) * D_MODEL + scol;

    // preload k0 = 0
    uint4 a0, a1, a2, a3, g0, g1, g2, g3;
    uint4 w0, w1, w2, w3, x0, x1, x2, x3;
    a0 = *(const uint4*)(ahp + 0);  a1 = *(const uint4*)(ahp + 8);
    a2 = *(const uint4*)(ahp + 16); a3 = *(const uint4*)(ahp + 24);
    w0 = *(const uint4*)(whp + 0);  w1 = *(const uint4*)(whp + 8);
    w2 = *(const uint4*)(whp + 16); w3 = *(const uint4*)(whp + 24);
    if (split) {
        g0 = *(const uint4*)(alp + 0);  g1 = *(const uint4*)(alp + 8);
        g2 = *(const uint4*)(alp + 16); g3 = *(const uint4*)(alp + 24);
        x0 = *(const uint4*)(wlp + 0);  x1 = *(const uint4*)(wlp + 8);
        x2 = *(const uint4*)(wlp + 16); x3 = *(const uint4*)(wlp + 24);
    }

    for (int k0 = 0; k0 < D_MODEL; k0 += 64) {
        __syncthreads();
        unsigned short* as = &Ah[srow * GLDK + scol];
        *(uint4*)(as + 0) = a0; *(uint4*)(as + 8)  = a1;
        *(uint4*)(as + 16) = a2; *(uint4*)(as + 24) = a3;
        unsigned short* ws = &Whs[srow * GLDK + scol];
        *(uint4*)(ws + 0) = w0; *(uint4*)(ws + 8)  = w1;
        *(uint4*)(ws + 16) = w2; *(uint4*)(ws + 24) = w3;
        if (split) {
            unsigned short* als = &Al[srow * GLDK + scol];
            *(uint4*)(als + 0) = g0; *(uint4*)(als + 8)  = g1;
            *(uint4*)(als + 16) = g2; *(uint4*)(als + 24) = g3;
            unsigned short* wl2 = &Wls[srow * GLDK + scol];
            *(uint4*)(wl2 + 0) = x0; *(uint4*)(wl2 + 8)  = x1;
            *(uint4*)(wl2 + 16) = x2; *(uint4*)(wl2 + 24) = x3;
        }
        __syncthreads();

        // issue NEXT iteration's loads (latency hides under the MFMA phase)
        if (k0 + 64 < D_MODEL) {
            ahp += 64; alp += 64; whp += 64; wlp += 64;
            a0 = *(const uint4*)(ahp + 0);  a1 = *(const uint4*)(ahp + 8);
            a2 = *(const uint4*)(ahp + 16); a3 = *(const uint4*)(ahp + 24);
            w0 = *(const uint4*)(whp + 0);  w1 = *(const uint4*)(whp + 8);
            w2 = *(const uint4*)(whp + 16); w3 = *(const uint4*)(whp + 24);
            if (split) {
                g0 = *(const uint4*)(alp + 0);  g1 = *(const uint4*)(alp + 8);
                g2 = *(const uint4*)(alp + 16); g3 = *(const uint4*)(alp + 24);
                x0 = *(const uint4*)(wlp + 0);  x1 = *(const uint4*)(wlp + 8);
                x2 = *(const uint4*)(wlp + 16); x3 = *(const uint4*)(wlp + 24);
            }
        }

        #pragma unroll
        for (int kc = 0; kc < 64; kc += 32) {
            bh8 ahf[4], whf[4];
            #pragma unroll
            for (int i = 0; i < 4; i++)
                ahf[i] = *(bh8*)&Ah[(wm + i * 16 + l15) * GLDK + kc + q4 * 8];
            #pragma unroll
            for (int j = 0; j < 4; j++)
                whf[j] = *(bh8*)&Whs[(wn + j * 16 + l15) * GLDK + kc + q4 * 8];
            #pragma unroll
            for (int i = 0; i < 4; i++)
                #pragma unroll
                for (int j = 0; j < 4; j++)
                    acc[i][j] = __builtin_amdgcn_mfma_f32_16x16x32_bf16(ahf[i], whf[j], acc[i][j], 0, 0, 0);
            if (split) {
                bh8 alf[4], wlf[4];
                #pragma unroll
                for (int i = 0; i < 4; i++)
                    alf[i] = *(bh8*)&Al[(wm + i * 16 + l15) * GLDK + kc + q4 * 8];
                #pragma unroll
                for (int j = 0; j < 4; j++)
                    wlf[j] = *(bh8*)&Wls[(wn + j * 16 + l15) * GLDK + kc + q4 * 8];
                #pragma unroll
                for (int i = 0; i < 4; i++)
                    #pragma unroll
                    for (int j = 0; j < 4; j++) {
                        acc[i][j] = __builtin_amdgcn_mfma_f32_16x16x32_bf16(ahf[i], wlf[j], acc[i][j], 0, 0, 0);
                        acc[i][j] = __builtin_amdgcn_mfma_f32_16x16x32_bf16(alf[i], whf[j], acc[i][j], 0, 0, 0);
                    }
            }
        }
    }

    if (split) {
        int hh = (bn + wn) >> 6;
        float bv[4];
        #pragma unroll
        for (int j = 0; j < 4; j++) bv[j] = Bi[bn + wn + j * 16 + l15];
        #pragma unroll
        for (int i = 0; i < 4; i++) {
            #pragma unroll
            for (int r = 0; r < 4; r++) {
                int row = bm + wm + i * 16 + q4 * 4 + r;
                int bb = row >> 10, tt = row & 1023;
                float vv[4]; float ss = 0.f;
                #pragma unroll
                for (int j = 0; j < 4; j++) {
                    vv[j] = acc[i][j][r] + bv[j];
                    ss += vv[j] * vv[j];
                }
                ss += __shfl_xor(ss, 1); ss += __shfl_xor(ss, 2);
                ss += __shfl_xor(ss, 4); ss += __shfl_xor(ss, 8);
                float rms = sqrtf(ss * (1.0f / 64.0f));
                unsigned short* kp = Yk + (((size_t)(bb * NHEAD + hh)) * T_SEQ + tt) * 128;
                #pragma unroll
                for (int j = 0; j < 4; j++) {
                    float xn = vv[j] / (rms + 1e-6f);
                    unsigned short hi = f2bf(xn);
                    unsigned short lo = f2bf(xn - bf2f(hi));
                    kp[j * 16 + l15]      = hi;
                    kp[64 + j * 16 + l15] = lo;
                }
            }
        }
    } else {
        #pragma unroll
        for (int j = 0; j < 4; j++) {
            int col = bn + wn + j * 16 + l15;
            int hh = col >> 6, dd = col & 63;
            float bvv = Bi[col];
            #pragma unroll
            for (int i = 0; i < 4; i++) {
                int row0 = bm + wm + i * 16 + q4 * 4;
                int bb = row0 >> 10, tt = row0 & 1023;
                uint2 u;
                u.x = (unsigned int)f2bf(acc[i][j][0] + bvv) | ((unsigned int)f2bf(acc[i][j][1] + bvv) << 16);
                u.y = (unsigned int)f2bf(acc[i][j][2] + bvv) | ((unsigned int)f2bf(acc[i][j][3] + bvv) << 16);
                *(uint2*)(Yv + ((size_t)(bb * NHEAD + hh) * HDIM + dd) * T_SEQ + tt) = u;
            }
        }
    }
}

// ---------------------------------------------------------------------------
// MFMA flash attention (r12 structure) with round-16 LOAD-BALANCED block
// decode: the old qt = 15-(rest&15) put the SAME qt on all 4 blocks
// resident on a CU (rest = c, c+32, c+64, c+96 share rest&15) -> 4..64
// iteration-units per CU vs ideal 34 (occupancy 18.5%). New decode:
// v=rest&15, k=rest>>5 -> qt = {v, 15-v, (v+4)&15, (11-v)&15}[k], b=k,
// h=((rest>>4)&1)*8+low. Bijective, and each CU's 4 resident blocks sum
// to exactly 34 units. Pure index permutation — math unchanged.
// ---------------------------------------------------------------------------
#define KST 72

__global__ __launch_bounds__(256, 4) void attn_kernel(
    const unsigned short* __restrict__ Qsg,   // [row][64 uints] = (hi,lo) pairs
    const unsigned short* __restrict__ Ksg,   // [row][128] = 64 hi | 64 lo
    const unsigned short* __restrict__ Vtg,   // [(bh)*64+d][1024] bf16
    unsigned short* __restrict__ Ctx, double* __restrict__ He)
{
    __shared__ unsigned short Kh[64 * KST];
    __shared__ unsigned short Kl[64 * KST];
    __shared__ unsigned short Vt[64 * KST];
    __shared__ unsigned short Ps[4][16 * KST];

    int tid = threadIdx.x;
    int blk = blockIdx.x;
    int low = blk & 7, rest = blk >> 3;
    // ---- load-balanced decode (r16) ----
    int v  = rest & 15;
    int mk = (rest >> 4) & 1;
    int k  = rest >> 5;                       // 0..3
    int qt = (k == 0) ? v
           : (k == 1) ? (15 - v)
           : (k == 2) ? ((v + 4) & 15)
                      : ((11 - v) & 15);
    int h   = mk * 8 + low;
    int b   = k;
    int bh = b * NHEAD + h;
    size_t rbase = (size_t)bh * T_SEQ;

    int wave = tid >> 6, lane = tid & 63;
    int l15 = lane & 15, rg = lane >> 4;
    int srow = tid >> 2;
    int scol = (tid & 3) * 16;

    int qrow = qt * 64 + wave * 16 + l15;

    bh8 qf[2][2];
    {
        const unsigned int* qp32 = (const unsigned int*)(Qsg + (rbase + qrow) * 128);
        uint4 a = *(const uint4*)(qp32 + rg * 8);
        uint4 c = *(const uint4*)(qp32 + rg * 8 + 4);
        uint4 d = *(const uint4*)(qp32 + 32 + rg * 8);
        uint4 e = *(const uint4*)(qp32 + 32 + rg * 8 + 4);
        unsigned int hv[4], lv[4];
        hv[0] = __builtin_amdgcn_perm(a.y, a.x, 0x05040100u);
        hv[1] = __builtin_amdgcn_perm(a.w, a.z, 0x05040100u);
        hv[2] = __builtin_amdgcn_perm(c.y, c.x, 0x05040100u);
        hv[3] = __builtin_amdgcn_perm(c.w, c.z, 0x05040100u);
        lv[0] = __builtin_amdgcn_perm(a.y, a.x, 0x07060302u);
        lv[1] = __builtin_amdgcn_perm(a.w, a.z, 0x07060302u);
        lv[2] = __builtin_amdgcn_perm(c.y, c.x, 0x07060302u);
        lv[3] = __builtin_amdgcn_perm(c.w, c.z, 0x07060302u);
        qf[0][0] = *(bh8*)hv;                 // hi, cols rg*8..+7
        qf[1][0] = *(bh8*)lv;                 // lo, cols rg*8..+7
        hv[0] = __builtin_amdgcn_perm(d.y, d.x, 0x05040100u);
        hv[1] = __builtin_amdgcn_perm(d.w, d.z, 0x05040100u);
        hv[2] = __builtin_amdgcn_perm(e.y, e.x, 0x05040100u);
        hv[3] = __builtin_amdgcn_perm(e.w, e.z, 0x05040100u);
        lv[0] = __builtin_amdgcn_perm(d.y, d.x, 0x07060302u);
        lv[1] = __builtin_amdgcn_perm(d.w, d.z, 0x07060302u);
        lv[2] = __builtin_amdgcn_perm(e.y, e.x, 0x07060302u);
        lv[3] = __builtin_amdgcn_perm(e.w, e.z, 0x07060302u);
        qf[0][1] = *(bh8*)hv;                 // hi, cols 32+rg*8..+7
        qf[1][1] = *(bh8*)lv;                 // lo, cols 32+rg*8..+7
    }

    float m = -1e30f, l = 0.f, s2 = 0.f;
    f32x4 o[4];
    #pragma unroll
    for (int n = 0; n < 4; n++) o[n] = (f32x4)0.f;

    unsigned short* myPs = &Ps[wave][0];
    const unsigned short* vbase = Vtg + (size_t)bh * HDIM * T_SEQ;

    for (int kt = 0; kt <= qt; ++kt) {
        const unsigned short* krow = Ksg + (rbase + kt * 64 + srow) * 128;
        uint4 kh0 = *(const uint4*)(krow + scol);
        uint4 kh1 = *(const uint4*)(krow + scol + 8);
        uint4 kl0 = *(const uint4*)(krow + 64 + scol);
        uint4 kl1 = *(const uint4*)(krow + 64 + scol + 8);
        const unsigned short* vrow = vbase + (size_t)srow * T_SEQ + kt * 64 + scol;
        uint4 vv0 = *(const uint4*)(vrow);
        uint4 vv1 = *(const uint4*)(vrow + 8);

        __syncthreads();
        *(uint4*)&Kh[srow * KST + scol]     = kh0;
        *(uint4*)&Kh[srow * KST + scol + 8] = kh1;
        *(uint4*)&Kl[srow * KST + scol]     = kl0;
        *(uint4*)&Kl[srow * KST + scol + 8] = kl1;
        *(uint4*)&Vt[srow * KST + scol]     = vv0;
        *(uint4*)&Vt[srow * KST + scol + 8] = vv1;
        __syncthreads();

        f32x4 s[4];
        #pragma unroll
        for (int n = 0; n < 4; n++) s[n] = (f32x4)0.f;
        #pragma unroll
        for (int n = 0; n < 4; n++) {
            const unsigned short* kr = &Kh[(n * 16 + l15) * KST + rg * 8];
            const unsigned short* lr = &Kl[(n * 16 + l15) * KST + rg * 8];
            bh8 ah0 = *(const bh8*)(kr);
            bh8 ah1 = *(const bh8*)(kr + 32);
            bh8 al0 = *(const bh8*)(lr);
            bh8 al1 = *(const bh8*)(lr + 32);
            s[n] = __builtin_amdgcn_mfma_f32_16x16x32_bf16(ah0, qf[0][0], s[n], 0, 0, 0);
            s[n] = __builtin_amdgcn_mfma_f32_16x16x32_bf16(ah1, qf[0][1], s[n], 0, 0, 0);
            s[n] = __builtin_amdgcn_mfma_f32_16x16x32_bf16(ah0, qf[1][0], s[n], 0, 0, 0);
            s[n] = __builtin_amdgcn_mfma_f32_16x16x32_bf16(ah1, qf[1][1], s[n], 0, 0, 0);
            s[n] = __builtin_amdgcn_mfma_f32_16x16x32_bf16(al0, qf[0][0], s[n], 0, 0, 0);
            s[n] = __builtin_amdgcn_mfma_f32_16x16x32_bf16(al1, qf[0][1], s[n], 0, 0, 0);
        }

        if (kt == qt) {
            #pragma unroll
            for (int n = 0; n < 4; n++)
                #pragma unroll
                for (int e2 = 0; e2 < 4; e2++)
                    if (n * 16 + rg * 4 + e2 > wave * 16 + l15) s[n][e2] = -1e30f;
        }

        float mx = -1e30f;
        #pragma unroll
        for (int n = 0; n < 4; n++)
            #pragma unroll
            for (int e2 = 0; e2 < 4; e2++) mx = fmaxf(mx, s[n][e2]);
        mx = fmaxf(mx, __shfl_xor(mx, 16));
        mx = fmaxf(mx, __shfl_xor(mx, 32));
        float mn = fmaxf(m, mx);
        float alpha = __expf(m - mn);
        m = mn;
        float rs = 0.f, rs2 = 0.f;
        #pragma unroll
        for (int n = 0; n < 4; n++)
            #pragma unroll
            for (int e2 = 0; e2 < 4; e2++) {
                float pv = __expf(s[n][e2] - mn);
                s[n][e2] = pv;
                rs += pv; rs2 += pv * pv;
            }
        rs  += __shfl_xor(rs, 16);  rs  += __shfl_xor(rs, 32);
        rs2 += __shfl_xor(rs2, 16); rs2 += __shfl_xor(rs2, 32);
        l  = l * alpha + rs;
        s2 = s2 * alpha * alpha + rs2;

        #pragma unroll
        for (int n = 0; n < 4; n++) {
            uint2 u;
            u.x = (unsigned int)f2bf(s[n][0]) | ((unsigned int)f2bf(s[n][1]) << 16);
            u.y = (unsigned int)f2bf(s[n][2]) | ((unsigned int)f2bf(s[n][3]) << 16);
            *(uint2*)&myPs[l15 * KST + n * 16 + rg * 4] = u;
        }
        bh8 pf0 = *(bh8*)&myPs[l15 * KST + rg * 8];
        bh8 pf1 = *(bh8*)&myPs[l15 * KST + 32 + rg * 8];

        #pragma unroll
        for (int n = 0; n < 4; n++) {
            o[n] *= alpha;
            const unsigned short* vr = &Vt[(n * 16 + l15) * KST + rg * 8];
            bh8 v0 = *(const bh8*)(vr);
            bh8 v1 = *(const bh8*)(vr + 32);
            o[n] = __builtin_amdgcn_mfma_f32_16x16x32_bf16(v0, pf0, o[n], 0, 0, 0);
            o[n] = __builtin_amdgcn_mfma_f32_16x16x32_bf16(v1, pf1, o[n], 0, 0, 0);
        }
    }

    float linv = 1.f / l;
    float en = (rg == 0) ? s2 * linv * linv : 0.f;
    en += __shfl_xor(en, 1); en += __shfl_xor(en, 2);
    en += __shfl_xor(en, 4); en += __shfl_xor(en, 8);
    if (lane == 0) atomicAdd(&He[bh], (double)en);

    unsigned short* cp = Ctx + ((size_t)b * T_SEQ + qrow) * D_MODEL + h * HDIM;
    #pragma unroll
    for (int n = 0; n < 4; n++) {
        uint2 u;
        u.x = (unsigned int)f2bf(o[n][0] * linv) | ((unsigned int)f2bf(o[n][1] * linv) << 16);
        u.y = (unsigned int)f2bf(o[n][2] * linv) | ((unsigned int)f2bf(o[n][3] * linv) << 16);
        *(uint2*)(cp + n * 16 + rg * 4) = u;
    }
}

// ---------------------------------------------------------------------------
// Out-projection with FUSED head selection + UNIFORM MASK-SKIP (verified).
// ---------------------------------------------------------------------------
__global__ __launch_bounds__(256, 2) void gemm_obf(
    const unsigned short* __restrict__ A, const unsigned short* __restrict__ W,
    const float* __restrict__ Bi, float* __restrict__ Y,
    const double* __restrict__ He)
{
    __shared__ unsigned short As[128 * GLDK];
    __shared__ unsigned short Ws[128 * GLDK];
    __shared__ double hs[34];       // [0..15] e, [16..31] p/terms, [32] sum
    __shared__ float maskS[NHEAD];

    int tid  = threadIdx.x;
    int blk  = blockIdx.x;
    int low  = blk & 7, rest = blk >> 3;
    int bn   = (rest & 7) * 128;
    int bm   = (((rest >> 3) << 3) + low) * 128;
    int batch = bm >> 10;

    // ---- fused headsel (per-block, deterministic)
    if (tid < NHEAD) hs[tid] = He[batch * NHEAD + tid] * (1.0 / (1024.0 * 1024.0));
    __syncthreads();
    if (tid < NHEAD) {
        double mx = hs[0];
        for (int h2 = 1; h2 < NHEAD; h2++) mx = fmax(mx, hs[h2]);
        hs[NHEAD + tid] = exp(hs[tid] - mx);
    }
    __syncthreads();
    if (tid == 0) {
        double s = 0.0;
        for (int h2 = 0; h2 < NHEAD; h2++) s += hs[NHEAD + h2];
        hs[32] = s;
    }
    __syncthreads();
    if (tid < NHEAD) {
        double ph = hs[NHEAD + tid] / hs[32];
        hs[NHEAD + tid] = ph * log(ph + 1e-9);
    }
    __syncthreads();
    if (tid == 0) {
        double ent = 0.0;
        for (int h2 = 0; h2 < NHEAD; h2++) ent -= hs[NHEAD + h2];
        double entn = ent / log(16.0);
        entn = fmin(fmax(entn, 0.0), 1.0);
        int keep = (int)rint(2.0 + entn * 4.0);
        if (keep < 1) keep = 1;
        if (keep > NHEAD) keep = NHEAD;
        double srt[NHEAD];
        for (int h2 = 0; h2 < NHEAD; h2++) srt[h2] = hs[h2];
        for (int i = 1; i < NHEAD; i++) {
            double v = srt[i]; int j = i - 1;
            while (j >= 0 && srt[j] < v) { srt[j + 1] = srt[j]; j--; }
            srt[j + 1] = v;
        }
        double th = srt[keep - 1];
        for (int h2 = 0; h2 < NHEAD; h2++)
            maskS[h2] = (hs[h2] >= th) ? 1.0f : 0.0f;
    }
    __syncthreads();

    int wave = tid >> 6, lane = tid & 63;
    int l15  = lane & 15, q4 = lane >> 4;
    int wm   = (wave >> 1) * 64, wn = (wave & 1) * 64;
    int srow = tid >> 1;
    int scol = (tid & 1) * 32;

    f32x4 acc[4][4];
    #pragma unroll
    for (int i = 0; i < 4; i++)
        #pragma unroll
        for (int j = 0; j < 4; j++) acc[i][j] = (f32x4)0.f;

    const unsigned short* ap = A + (size_t)(bm + srow) * D_MODEL + scol;
    const unsigned short* wp = W + (size_t)(bn + srow) * D_MODEL + scol;

    for (int k0 = 0; k0 < D_MODEL; k0 += 64) {
        // UNIFORM skip: pruned head slab contributes exactly 0
        if (maskS[k0 >> 6] == 0.f) { ap += 64; wp += 64; continue; }

        uint4 a0 = *(const uint4*)(ap + 0),  a1 = *(const uint4*)(ap + 8);
        uint4 a2 = *(const uint4*)(ap + 16), a3 = *(const uint4*)(ap + 24);
        uint4 w0 = *(const uint4*)(wp + 0),  w1 = *(const uint4*)(wp + 8);
        uint4 w2 = *(const uint4*)(wp + 16), w3 = *(const uint4*)(wp + 24);
        ap += 64; wp += 64;
        __syncthreads();
        unsigned short* as = &As[srow * GLDK + scol];
        *(uint4*)(as + 0) = a0; *(uint4*)(as + 8)  = a1;
        *(uint4*)(as + 16) = a2; *(uint4*)(as + 24) = a3;
        unsigned short* ws = &Ws[srow * GLDK + scol];
        *(uint4*)(ws + 0) = w0; *(uint4*)(ws + 8)  = w1;
        *(uint4*)(ws + 16) = w2; *(uint4*)(ws + 24) = w3;
        __syncthreads();

        #pragma unroll
        for (int kc = 0; kc < 64; kc += 32) {
            bh8 af[4], wf[4];
            #pragma unroll
            for (int i = 0; i < 4; i++)
                af[i] = *(bh8*)&As[(wm + i * 16 + l15) * GLDK + kc + q4 * 8];
            #pragma unroll
            for (int j = 0; j < 4; j++)
                wf[j] = *(bh8*)&Ws[(wn + j * 16 + l15) * GLDK + kc + q4 * 8];
            #pragma unroll
            for (int i = 0; i < 4; i++)
                #pragma unroll
                for (int j = 0; j < 4; j++)
                    acc[i][j] = __builtin_amdgcn_mfma_f32_16x16x32_bf16(af[i], wf[j], acc[i][j], 0, 0, 0);
        }
    }

    #pragma unroll
    for (int j = 0; j < 4; j++) {
        int col = bn + wn + j * 16 + l15;
        float bv = Bi[col];
        #pragma unroll
        for (int i = 0; i < 4; i++) {
            int row = bm + wm + i * 16 + q4 * 4;
            #pragma unroll
            for (int r = 0; r < 4; r++)
                Y[(size_t)(row + r) * D_MODEL + col] = acc[i][j][r] + bv;
        }
    }
}

// ---------------------------------------------------------------------------
extern "C" void kernel_launch(void* const* d_in, const int* in_sizes, int n_in,
                              void* d_out, int out_size, void* d_ws, size_t ws_size,
                              hipStream_t stream)
{
    (void)in_sizes; (void)n_in; (void)out_size; (void)ws_size;
    const float* x  = (const float*)d_in[0];
    const float* qw = (const float*)d_in[1];
    const float* qb = (const float*)d_in[2];
    const float* kw = (const float*)d_in[3];
    const float* kb = (const float*)d_in[4];
    const float* vw = (const float*)d_in[5];
    const float* vb = (const float*)d_in[6];
    const float* ow = (const float*)d_in[7];
    const float* ob = (const float*)d_in[8];
    float* out = (float*)d_out;

    // Memory map (sequential pipeline — dig overlay safe):
    //   0-16   qbf (uint-pair rows [(b*16+h)*1024+t][64]: (hi_c,lo_c))
    //  16-32   kbf  (norm-split bf16: 65536 rows x 256 B = 16 MB)
    //  32-40   vt   (V^T bf16, 8 MB)
    //  40-48   ctxb (bf16, 8 MB)
    //  32-48   dig  (16 MB, FRAGMENT-MAJOR; OVERLAYS vt+ctxb; fully consumed
    //               by gemm_q_i8 before gemm_kv writes vt / attn writes ctxb)
    //  48-56   kwh, kwl, vwb, owb (2 MB each)
    //  56-57   sg (fragment-major)
    //  57-58   he (512 B)
    //  58-66   xh (bf16 hi plane of x, row-major, 8 MB)
    //  66-74   xl (bf16 lo plane of x, row-major, 8 MB)
    char* base = (char*)d_ws;
    const size_t MB = (size_t)1024 * 1024;
    unsigned short* qbf  = (unsigned short*)(base);
    unsigned short* kbf  = (unsigned short*)(base + 16 * MB);
    unsigned short* vt   = (unsigned short*)(base + 32 * MB);
    unsigned short* ctxb = (unsigned short*)(base + 40 * MB);
    signed char*    dig  = (signed char*)(base + 32 * MB);
    unsigned short* kwh  = (unsigned short*)(base + 48 * MB);
    unsigned short* kwl  = (unsigned short*)(base + 50 * MB);
    unsigned short* vwb  = (unsigned short*)(base + 52 * MB);
    unsigned short* owb  = (unsigned short*)(base + 54 * MB);
    signed char*    sg   = (signed char*)(base + 56 * MB);
    double*         he   = (double*)(base + 57 * MB);
    unsigned short* xh   = (unsigned short*)(base + 58 * MB);
    unsigned short* xl   = (unsigned short*)(base + 66 * MB);

    hipMemsetAsync(he, 0, 64 * sizeof(double), stream);

    // weights cast + x digitize (fragment-major) + x hi/lo split + qw sign
    cast_prep<<<4096, 256, 0, stream>>>(kw, kwh, kwl, vw, vwb, ow, owb,
                                        x, dig, xh, xl, qw, sg);
    // q projection: barrier-free, contiguous fragment loads + fused RMS/top-k
    gemm_q_i8<<<1024, 256, 0, stream>>>(dig, sg, qb, qbf);
    // k + v projection: LDS-staged, pre-split A + register prefetch
    gemm_kv<<<512, 256, 0, stream>>>(xh, xl, kwh, kwl, kb, vwb, vb, kbf, vt);
    // attention: load-balanced qt decode (r16)
    attn_kernel<<<1024, 256, 0, stream>>>(qbf, kbf, vt, ctxb, he);
    // out-projection with fused head selection + mask-skip
    gemm_obf<<<256, 256, 0, stream>>>(ctxb, owb, ob, out, he);
}